// Round 6
// baseline (450.900 us; speedup 1.0000x reference)
//
#include <hip/hip_runtime.h>
#include <math.h>

// x: [4][4096][2048] f32, importance: [4][4096] f32, W: [2048][64] f32,
// b: [64] f32, neuron_emb: [4096][64] f32
// out: [4][5120] f32  (wC 2048 | wQ 1024 | wK 1024 (==wQ) | wV 1024)
#define D_IN   2048

typedef __bf16 bf16x8 __attribute__((ext_vector_type(8)));
typedef float  f32x4  __attribute__((ext_vector_type(4)));

// ---------------------------------------------------------------------------
// K0: prep.  blocks [0,1024): normalize neuron_emb rows + split hi/lo bf16.
//            blocks [1024,1536): transpose + split W -> wt[64][2048].
__global__ __launch_bounds__(256) void k_prep(const float* __restrict__ emb,
                                              const float* __restrict__ W,
                                              __bf16* __restrict__ e_hi,
                                              __bf16* __restrict__ e_lo,
                                              __bf16* __restrict__ wt_hi,
                                              __bf16* __restrict__ wt_lo) {
    int blk = blockIdx.x, t = threadIdx.x;
    if (blk < 1024) {
        int gid  = blk * 256 + t;
        int row  = gid >> 6;
        int lane = gid & 63;
        float v  = emb[row * 64 + lane];
        float ss = v * v;
#pragma unroll
        for (int m = 32; m >= 1; m >>= 1) ss += __shfl_xor(ss, m);
        float nv = v / sqrtf(ss);
        __bf16 hb = (__bf16)nv;
        e_hi[row * 64 + lane] = hb;
        e_lo[row * 64 + lane] = (__bf16)(nv - (float)hb);
    } else {
        int gid = (blk - 1024) * 256 + t;   // 131072 total
        int c   = gid >> 11;
        int k   = gid & 2047;
        float v = W[k * 64 + c];
        __bf16 hb = (__bf16)v;
        wt_hi[c * 2048 + k] = hb;
        wt_lo[c * 2048 + k] = (__bf16)(v - (float)hb);
    }
}

// ---------------------------------------------------------------------------
// K1: FUSED h-GEMM + Z-pass + weighted-accumulate.
// 512 blocks x 32 rows, 512 threads (8 waves).
// Phase H: wave w computes h-partial over K slice [w*256,(w+1)*256) with
//   16x16x32 split-bf16 MFMA (2 row-tiles x 4 col-tiles), waves combine via
//   LDS atomicAdd, wave 0 adds bias and stores h as XOR-swizzled hi/lo bf16.
// Phase Z/ACC: per segment, sweep neurons (8 waves x 32-neuron slices,
//   chunk=256), 16x16x32 MFMA, zc[8]/cf[8] per lane, 4 indep acc chains.
// All MFMA fragment layouts identical to the validated k_hgemm_mfma:
//   A: row=lane&15, k=(lane>>4)*8+j (+32*ks); B: col=lane&15, same k;
//   C: col=lane&15, row=(lane>>4)*4+r.
#define CHUNK_MFMA(N0)                                                        \
    {                                                                         \
        bf16x8 bh[2][2];                                                      \
        _Pragma("unroll") for (int ct = 0; ct < 2; ++ct)                      \
        _Pragma("unroll") for (int ks = 0; ks < 2; ++ks)                      \
            bh[ct][ks] = *(const bf16x8*)(e_hi +                              \
                (size_t)((N0) + ct * 16 + l15) * 64 + ks * 32 + kg * 8);      \
        _Pragma("unroll") for (int rt = 0; rt < 2; ++rt)                      \
        _Pragma("unroll") for (int ct = 0; ct < 2; ++ct)                      \
        _Pragma("unroll") for (int ks = 0; ks < 2; ++ks)                      \
            acc[rt][ct] = __builtin_amdgcn_mfma_f32_16x16x32_bf16(            \
                a_hi[rt][ks], bh[ct][ks], acc[rt][ct], 0, 0, 0);              \
        _Pragma("unroll") for (int rt = 0; rt < 2; ++rt)                      \
        _Pragma("unroll") for (int ct = 0; ct < 2; ++ct)                      \
        _Pragma("unroll") for (int ks = 0; ks < 2; ++ks)                      \
            acc[rt][ct] = __builtin_amdgcn_mfma_f32_16x16x32_bf16(            \
                a_lo[rt][ks], bh[ct][ks], acc[rt][ct], 0, 0, 0);              \
        bf16x8 bl[2][2];                                                      \
        _Pragma("unroll") for (int ct = 0; ct < 2; ++ct)                      \
        _Pragma("unroll") for (int ks = 0; ks < 2; ++ks)                      \
            bl[ct][ks] = *(const bf16x8*)(e_lo +                              \
                (size_t)((N0) + ct * 16 + l15) * 64 + ks * 32 + kg * 8);      \
        _Pragma("unroll") for (int rt = 0; rt < 2; ++rt)                      \
        _Pragma("unroll") for (int ct = 0; ct < 2; ++ct)                      \
        _Pragma("unroll") for (int ks = 0; ks < 2; ++ks)                      \
            acc[rt][ct] = __builtin_amdgcn_mfma_f32_16x16x32_bf16(            \
                a_hi[rt][ks], bl[ct][ks], acc[rt][ct], 0, 0, 0);              \
    }

__global__ __launch_bounds__(512, 4) void k_fused(
        const float* __restrict__ x,
        const __bf16* __restrict__ wt_hi, const __bf16* __restrict__ wt_lo,
        const float* __restrict__ bias,
        const __bf16* __restrict__ e_hi, const __bf16* __restrict__ e_lo,
        const float* __restrict__ imp, float* __restrict__ partials) {
    __shared__ float  h_acc[32][66];
    __shared__ __bf16 hb_hi[32][64];   // XOR-swizzled: colgrp' = colgrp ^ (row&7)
    __shared__ __bf16 hb_lo[32][64];
    __shared__ float  zs[8][4][8];

    int t    = threadIdx.x;
    int wave = t >> 6;
    int lane = t & 63;
    int l15  = lane & 15;
    int kg   = lane >> 4;          // 0..3
    int row0 = blockIdx.x * 32;

    // zero the f32 reduction buffer
    for (int i = t; i < 32 * 66; i += 512) ((float*)h_acc)[i] = 0.f;
    __syncthreads();

    // ---------------- Phase H: h = x @ W (this block's 32 rows) ------------
    {
        f32x4 hacc[2][4] = {};
        int kb0 = wave * 256;
#pragma unroll 2
        for (int ks = 0; ks < 8; ++ks) {
            int kb = kb0 + ks * 32 + kg * 8;
            bf16x8 ah[2], al[2];
#pragma unroll
            for (int rt = 0; rt < 2; ++rt) {
                const float* xp = x + (size_t)(row0 + rt * 16 + l15) * D_IN + kb;
                float4 a0 = *(const float4*)xp;
                float4 a1 = *(const float4*)(xp + 4);
                float av[8] = {a0.x, a0.y, a0.z, a0.w, a1.x, a1.y, a1.z, a1.w};
#pragma unroll
                for (int j = 0; j < 8; ++j) {
                    __bf16 hb = (__bf16)av[j];
                    ah[rt][j] = hb;
                    al[rt][j] = (__bf16)(av[j] - (float)hb);
                }
            }
            bf16x8 bh[4];
#pragma unroll
            for (int ct = 0; ct < 4; ++ct)
                bh[ct] = *(const bf16x8*)(wt_hi + (size_t)(ct * 16 + l15) * D_IN + kb);
#pragma unroll
            for (int rt = 0; rt < 2; ++rt)
#pragma unroll
                for (int ct = 0; ct < 4; ++ct)
                    hacc[rt][ct] = __builtin_amdgcn_mfma_f32_16x16x32_bf16(
                        ah[rt], bh[ct], hacc[rt][ct], 0, 0, 0);
#pragma unroll
            for (int rt = 0; rt < 2; ++rt)
#pragma unroll
                for (int ct = 0; ct < 4; ++ct)
                    hacc[rt][ct] = __builtin_amdgcn_mfma_f32_16x16x32_bf16(
                        al[rt], bh[ct], hacc[rt][ct], 0, 0, 0);
            bf16x8 bl[4];
#pragma unroll
            for (int ct = 0; ct < 4; ++ct)
                bl[ct] = *(const bf16x8*)(wt_lo + (size_t)(ct * 16 + l15) * D_IN + kb);
#pragma unroll
            for (int rt = 0; rt < 2; ++rt)
#pragma unroll
                for (int ct = 0; ct < 4; ++ct)
                    hacc[rt][ct] = __builtin_amdgcn_mfma_f32_16x16x32_bf16(
                        ah[rt], bl[ct], hacc[rt][ct], 0, 0, 0);
        }
        // combine the 8 waves' K-partials
#pragma unroll
        for (int rt = 0; rt < 2; ++rt)
#pragma unroll
            for (int ct = 0; ct < 4; ++ct)
#pragma unroll
                for (int r = 0; r < 4; ++r)
                    atomicAdd(&h_acc[rt * 16 + kg * 4 + r][ct * 16 + l15],
                              hacc[rt][ct][r]);
    }
    __syncthreads();
    if (wave == 0) {
        // bias + hi/lo split + swizzled store (one wave, 32x64)
#pragma unroll 4
        for (int row = 0; row < 32; ++row) {
            float v = h_acc[row][lane] + bias[lane];
            __bf16 hb = (__bf16)v;
            int c2 = ((((lane >> 3) ^ (row & 7)) << 3) | (lane & 7));
            hb_hi[row][c2] = hb;
            hb_lo[row][c2] = (__bf16)(v - (float)hb);
        }
    }
    __syncthreads();

    // ---------------- A fragments from swizzled LDS ------------------------
    bf16x8 a_hi[2][2], a_lo[2][2];
#pragma unroll
    for (int rt = 0; rt < 2; ++rt)
#pragma unroll
        for (int ks = 0; ks < 2; ++ks) {
            int row = rt * 16 + l15;
            int g   = ((ks * 4 + kg) ^ (l15 & 7)) * 8;
            a_hi[rt][ks] = *(const bf16x8*)&hb_hi[row][g];
            a_lo[rt][ks] = *(const bf16x8*)&hb_lo[row][g];
        }

    int b    = blockIdx.x >> 7;          // 128 blocks per batch
    int slot = blockIdx.x & 127;
    float* pbase = partials + ((size_t)(b * 128 + slot)) * 4096;

    // ---------------- Phase Z / ACC per segment ----------------------------
    const int segB[4] = {0, 2048, 3072, 4096};
    for (int sg = 0; sg < 3; ++sg) {
        float zc[2][4] = {};
        for (int nb = segB[sg]; nb < segB[sg + 1]; nb += 256) {
            int n0 = nb + wave * 32;
            f32x4 acc[2][2] = {};
            CHUNK_MFMA(n0)
#pragma unroll
            for (int rt = 0; rt < 2; ++rt)
#pragma unroll
                for (int r = 0; r < 4; ++r)
                    zc[rt][r] += __expf(acc[rt][0][r]) + __expf(acc[rt][1][r]);
        }
        // reduce over the 16 l15-lanes (cols within wave)
#pragma unroll
        for (int rt = 0; rt < 2; ++rt)
#pragma unroll
            for (int r = 0; r < 4; ++r) {
                float z = zc[rt][r];
#pragma unroll
                for (int m = 1; m < 16; m <<= 1) z += __shfl_xor(z, m);
                zc[rt][r] = z;
            }
        if (l15 == 0) {
#pragma unroll
            for (int rt = 0; rt < 2; ++rt)
#pragma unroll
                for (int r = 0; r < 4; ++r)
                    zs[wave][kg][rt * 4 + r] = zc[rt][r];
        }
        __syncthreads();
        float cf[2][4];
#pragma unroll
        for (int rt = 0; rt < 2; ++rt)
#pragma unroll
            for (int r = 0; r < 4; ++r) {
                float z = 0.f;
#pragma unroll
                for (int w = 0; w < 8; ++w) z += zs[w][kg][rt * 4 + r];
                cf[rt][r] = imp[row0 + rt * 16 + kg * 4 + r] / z;
            }
        __syncthreads();  // zs reused next segment
        for (int nb = segB[sg]; nb < segB[sg + 1]; nb += 256) {
            int n0 = nb + wave * 32;
            f32x4 acc[2][2] = {};
            CHUNK_MFMA(n0)
            float s0 = 0.f, s1 = 0.f;
#pragma unroll
            for (int rt = 0; rt < 2; ++rt)
#pragma unroll
                for (int r = 0; r < 4; ++r) {
                    s0 += cf[rt][r] * __expf(acc[rt][0][r]);
                    s1 += cf[rt][r] * __expf(acc[rt][1][r]);
                }
            // sum the 4 kg row-groups (lane bits 4,5)
            s0 += __shfl_xor(s0, 16); s0 += __shfl_xor(s0, 32);
            s1 += __shfl_xor(s1, 16); s1 += __shfl_xor(s1, 32);
            if (kg == 0) {
                pbase[n0 + l15]      = s0;
                pbase[n0 + 16 + l15] = s1;
            }
        }
    }
}

// ---------------------------------------------------------------------------
// K2: top-k sparsify with inlined 128-slot reduction.
// One block per (batch, segment) -> 12 blocks.
__global__ __launch_bounds__(256) void k_topk(const float* __restrict__ partials,
                                              float* __restrict__ out) {
    __shared__ float dv[2048];
    __shared__ float redv[4];
    __shared__ int   redi[4];
    __shared__ float selv[8];
    __shared__ int   seli[8];
    int blk = blockIdx.x;
    int b   = blk / 3;
    int sg  = blk - 3 * b;
    int t   = threadIdx.x;
    const int segStart[3] = {0, 2048, 3072};
    const int segLen[3]   = {2048, 1024, 1024};
    const int segK[3]     = {8, 4, 6};
    const int segOut[3]   = {0, 2048, 4096};
    int st = segStart[sg], len = segLen[sg], kk = segK[sg];
    // inline reduction of the 128 partial slots
    for (int n = t; n < len; n += 256) {
        const float* p = partials + (size_t)b * 128 * 4096 + st + n;
        float s0 = 0.f, s1 = 0.f, s2 = 0.f, s3 = 0.f;
#pragma unroll 4
        for (int sl = 0; sl < 128; sl += 4) {
            s0 += p[(size_t)(sl + 0) * 4096];
            s1 += p[(size_t)(sl + 1) * 4096];
            s2 += p[(size_t)(sl + 2) * 4096];
            s3 += p[(size_t)(sl + 3) * 4096];
        }
        dv[n] = (s0 + s1) + (s2 + s3);
    }
    __syncthreads();
    for (int it = 0; it < kk; ++it) {
        float bv = -3.0e38f;
        int   bi = 1 << 30;
        for (int n = t; n < len; n += 256) {
            float v = dv[n];
            if (v > bv) { bv = v; bi = n; }  // strict > keeps lowest idx
        }
#pragma unroll
        for (int m = 1; m < 64; m <<= 1) {
            float ov = __shfl_xor(bv, m);
            int   oi = __shfl_xor(bi, m);
            if (ov > bv || (ov == bv && oi < bi)) { bv = ov; bi = oi; }
        }
        if ((t & 63) == 0) { redv[t >> 6] = bv; redi[t >> 6] = bi; }
        __syncthreads();
        if (t == 0) {
            for (int w = 1; w < 4; ++w)
                if (redv[w] > bv || (redv[w] == bv && redi[w] < bi)) {
                    bv = redv[w]; bi = redi[w];
                }
            selv[it] = bv;
            seli[it] = bi;
            dv[bi] = -3.4e38f;
        }
        __syncthreads();
    }
    float sum = 0.f;
    for (int it = 0; it < kk; ++it) sum += selv[it];
    float inv = 1.0f / (sum + 1e-8f);
    for (int n = t; n < len; n += 256) {
        float v = 0.0f;
        for (int it = 0; it < kk; ++it)
            if (seli[it] == n) v = selv[it] * inv;
        out[b * 5120 + segOut[sg] + n] = v;
        if (sg == 1) out[b * 5120 + 3072 + n] = v;  // wK == wQ
    }
}

// ---------------------------------------------------------------------------
extern "C" void kernel_launch(void* const* d_in, const int* in_sizes, int n_in,
                              void* d_out, int out_size, void* d_ws, size_t ws_size,
                              hipStream_t stream) {
    (void)in_sizes; (void)n_in; (void)out_size; (void)ws_size;
    const float* x    = (const float*)d_in[0];
    const float* imp  = (const float*)d_in[1];
    const float* W    = (const float*)d_in[2];
    const float* bias = (const float*)d_in[3];
    const float* emb  = (const float*)d_in[4];
    float* out = (float*)d_out;

    // workspace layout (bytes): ~9.5 MB
    char* w = (char*)d_ws;
    __bf16* e_hi  = (__bf16*)w;  w += (size_t)4096 * 64 * 2;        // 512KB
    __bf16* e_lo  = (__bf16*)w;  w += (size_t)4096 * 64 * 2;        // 512KB
    __bf16* wt_hi = (__bf16*)w;  w += (size_t)64 * 2048 * 2;        // 256KB
    __bf16* wt_lo = (__bf16*)w;  w += (size_t)64 * 2048 * 2;        // 256KB
    float*  partials = (float*)w; w += (size_t)4 * 128 * 4096 * 4;  // 8MB

    hipLaunchKernelGGL(k_prep,  dim3(1536), dim3(256), 0, stream,
                       emb, W, e_hi, e_lo, wt_hi, wt_lo);
    hipLaunchKernelGGL(k_fused, dim3(512),  dim3(512), 0, stream,
                       x, wt_hi, wt_lo, bias, e_hi, e_lo, imp, partials);
    hipLaunchKernelGGL(k_topk,  dim3(12),   dim3(256), 0, stream,
                       partials, out);
}

// Round 7
// 363.188 us; speedup vs baseline: 1.2415x; 1.2415x over previous
//
#include <hip/hip_runtime.h>
#include <math.h>

// x: [4][4096][2048] f32, importance: [4][4096] f32, W: [2048][64] f32,
// b: [64] f32, neuron_emb: [4096][64] f32
// out: [4][5120] f32  (wC 2048 | wQ 1024 | wK 1024 (==wQ) | wV 1024)
#define D_IN   2048

typedef __bf16 bf16x8 __attribute__((ext_vector_type(8)));
typedef float  f32x4  __attribute__((ext_vector_type(4)));

#define mfma16 __builtin_amdgcn_mfma_f32_16x16x32_bf16

// ---------------------------------------------------------------------------
// K0: prep.  blocks [0,1024): normalize neuron_emb rows + split hi/lo bf16.
//            blocks [1024,1536): transpose + split W -> wt[64][2048].
//            blocks [1536,1600): zero dacc (16384 floats).
__global__ __launch_bounds__(256) void k_prep(const float* __restrict__ emb,
                                              const float* __restrict__ W,
                                              __bf16* __restrict__ e_hi,
                                              __bf16* __restrict__ e_lo,
                                              __bf16* __restrict__ wt_hi,
                                              __bf16* __restrict__ wt_lo,
                                              float* __restrict__ dacc) {
    int blk = blockIdx.x, t = threadIdx.x;
    if (blk < 1024) {
        int gid  = blk * 256 + t;
        int row  = gid >> 6;
        int lane = gid & 63;
        float v  = emb[row * 64 + lane];
        float ss = v * v;
#pragma unroll
        for (int m = 32; m >= 1; m >>= 1) ss += __shfl_xor(ss, m);
        float nv = v / sqrtf(ss);
        __bf16 hb = (__bf16)nv;
        e_hi[row * 64 + lane] = hb;
        e_lo[row * 64 + lane] = (__bf16)(nv - (float)hb);
    } else if (blk < 1536) {
        int gid = (blk - 1024) * 256 + t;   // 131072 total
        int c   = gid >> 11;
        int k   = gid & 2047;
        float v = W[k * 64 + c];
        __bf16 hb = (__bf16)v;
        wt_hi[c * 2048 + k] = hb;
        wt_lo[c * 2048 + k] = (__bf16)(v - (float)hb);
    } else {
        dacc[(blk - 1536) * 256 + t] = 0.f;
    }
}

// ---------------------------------------------------------------------------
// K1: FUSED h-GEMM + Z-pass + weighted-accumulate (dacc via atomicAdd).
// 512 blocks x 32 rows, 512 threads (8 waves).
// Phase H: wave w computes h-partial over K slice [w*256,(w+1)*256), x loads
//   even/odd prefetched; waves combine via LDS atomicAdd; wave 0 adds bias,
//   splits hi/lo, stores XOR-swizzled in LDS.
// Phase Z/ACC: per segment, sweep neurons; half-chunk (16-neuron) pipelined
//   B-fragment double-buffer (qa/qb); 24 MFMAs + 8 exp per 32-neuron chunk.
__global__ __launch_bounds__(512, 4) void k_fused(
        const float* __restrict__ x,
        const __bf16* __restrict__ wt_hi, const __bf16* __restrict__ wt_lo,
        const float* __restrict__ bias,
        const __bf16* __restrict__ e_hi, const __bf16* __restrict__ e_lo,
        const float* __restrict__ imp, float* __restrict__ dacc) {
    __shared__ float  h_acc[32][66];
    __shared__ __bf16 hb_hi[32][64];   // XOR-swizzled: colgrp' = colgrp ^ (row&7)
    __shared__ __bf16 hb_lo[32][64];
    __shared__ float  zs[8][4][8];

    int t    = threadIdx.x;
    int wave = t >> 6;
    int lane = t & 63;
    int l15  = lane & 15;
    int kg   = lane >> 4;          // 0..3
    int row0 = blockIdx.x * 32;
    const f32x4 z4 = {0.f, 0.f, 0.f, 0.f};

    for (int i = t; i < 32 * 66; i += 512) ((float*)h_acc)[i] = 0.f;
    __syncthreads();

    // ---------------- Phase H: h = x @ W (this block's 32 rows) ------------
    {
        f32x4 hacc[2][4];
#pragma unroll
        for (int rt = 0; rt < 2; ++rt)
#pragma unroll
            for (int ct = 0; ct < 4; ++ct) hacc[rt][ct] = z4;
        int kb0 = wave * 256;
        const float* xr0 = x + (size_t)(row0 + l15) * D_IN + kb0 + kg * 8;
        const float* xr1 = xr0 + 16 * D_IN;
        float4 xe0, xe1, xe2, xe3, xo0, xo1, xo2, xo3;

#define LDX(B, KS) { B##0 = *(const float4*)(xr0 + (KS) * 32); \
                     B##1 = *(const float4*)(xr0 + (KS) * 32 + 4); \
                     B##2 = *(const float4*)(xr1 + (KS) * 32); \
                     B##3 = *(const float4*)(xr1 + (KS) * 32 + 4); }
#define CVT8(DH, DL, V0, V1) { \
    float av[8] = {V0.x, V0.y, V0.z, V0.w, V1.x, V1.y, V1.z, V1.w}; \
    _Pragma("unroll") for (int j = 0; j < 8; ++j) { \
        __bf16 hb = (__bf16)av[j]; DH[j] = hb; \
        DL[j] = (__bf16)(av[j] - (float)hb); } }
#define HCOMP(B, KS) { \
    bf16x8 ah[2], al[2], bw[4]; \
    CVT8(ah[0], al[0], B##0, B##1) \
    CVT8(ah[1], al[1], B##2, B##3) \
    int kb = kb0 + (KS) * 32 + kg * 8; \
    _Pragma("unroll") for (int ct = 0; ct < 4; ++ct) \
        bw[ct] = *(const bf16x8*)(wt_hi + (size_t)(ct * 16 + l15) * D_IN + kb); \
    _Pragma("unroll") for (int rt = 0; rt < 2; ++rt) \
    _Pragma("unroll") for (int ct = 0; ct < 4; ++ct) \
        hacc[rt][ct] = mfma16(ah[rt], bw[ct], hacc[rt][ct], 0, 0, 0); \
    _Pragma("unroll") for (int rt = 0; rt < 2; ++rt) \
    _Pragma("unroll") for (int ct = 0; ct < 4; ++ct) \
        hacc[rt][ct] = mfma16(al[rt], bw[ct], hacc[rt][ct], 0, 0, 0); \
    _Pragma("unroll") for (int ct = 0; ct < 4; ++ct) \
        bw[ct] = *(const bf16x8*)(wt_lo + (size_t)(ct * 16 + l15) * D_IN + kb); \
    _Pragma("unroll") for (int rt = 0; rt < 2; ++rt) \
    _Pragma("unroll") for (int ct = 0; ct < 4; ++ct) \
        hacc[rt][ct] = mfma16(ah[rt], bw[ct], hacc[rt][ct], 0, 0, 0); }

        LDX(xe, 0)
        LDX(xo, 1) HCOMP(xe, 0)
        LDX(xe, 2) HCOMP(xo, 1)
        LDX(xo, 3) HCOMP(xe, 2)
        LDX(xe, 4) HCOMP(xo, 3)
        LDX(xo, 5) HCOMP(xe, 4)
        LDX(xe, 6) HCOMP(xo, 5)
        LDX(xo, 7) HCOMP(xe, 6)
        HCOMP(xo, 7)
#undef LDX
#undef HCOMP

        // combine the 8 waves' K-partials
#pragma unroll
        for (int rt = 0; rt < 2; ++rt)
#pragma unroll
            for (int ct = 0; ct < 4; ++ct)
#pragma unroll
                for (int r = 0; r < 4; ++r)
                    atomicAdd(&h_acc[rt * 16 + kg * 4 + r][ct * 16 + l15],
                              hacc[rt][ct][r]);
    }
    __syncthreads();
    if (wave == 0) {
#pragma unroll 4
        for (int row = 0; row < 32; ++row) {
            float v = h_acc[row][lane] + bias[lane];
            __bf16 hb = (__bf16)v;
            int c2 = ((((lane >> 3) ^ (row & 7)) << 3) | (lane & 7));
            hb_hi[row][c2] = hb;
            hb_lo[row][c2] = (__bf16)(v - (float)hb);
        }
    }
    __syncthreads();

    // ---------------- A fragments from swizzled LDS ------------------------
    bf16x8 a_hi[2][2], a_lo[2][2];
#pragma unroll
    for (int rt = 0; rt < 2; ++rt)
#pragma unroll
        for (int ks = 0; ks < 2; ++ks) {
            int row = rt * 16 + l15;
            int g   = ((ks * 4 + kg) ^ (l15 & 7)) * 8;
            a_hi[rt][ks] = *(const bf16x8*)&hb_hi[row][g];
            a_lo[rt][ks] = *(const bf16x8*)&hb_lo[row][g];
        }

    int bb = blockIdx.x >> 7;            // batch (128 blocks per batch)
    float* dbase = dacc + bb * 4096;
    const __bf16* pe_hi = e_hi + l15 * 64 + kg * 8;
    const __bf16* pe_lo = e_lo + l15 * 64 + kg * 8;

#define LOADH(P, NN) { size_t off = (size_t)(NN) * 64; \
    P##H0 = *(const bf16x8*)(pe_hi + off); \
    P##H1 = *(const bf16x8*)(pe_hi + off + 32); \
    P##L0 = *(const bf16x8*)(pe_lo + off); \
    P##L1 = *(const bf16x8*)(pe_lo + off + 32); }
#define MFMAH(P, CT) { \
    _Pragma("unroll") for (int rt = 0; rt < 2; ++rt) { \
        f32x4 tt = acc[rt][CT]; \
        tt = mfma16(a_hi[rt][0], P##H0, tt, 0, 0, 0); \
        tt = mfma16(a_hi[rt][1], P##H1, tt, 0, 0, 0); \
        tt = mfma16(a_lo[rt][0], P##H0, tt, 0, 0, 0); \
        tt = mfma16(a_lo[rt][1], P##H1, tt, 0, 0, 0); \
        tt = mfma16(a_hi[rt][0], P##L0, tt, 0, 0, 0); \
        tt = mfma16(a_hi[rt][1], P##L1, tt, 0, 0, 0); \
        acc[rt][CT] = tt; } }

    bf16x8 qaH0, qaH1, qaL0, qaL1, qbH0, qbH1, qbL0, qbL1;

    // ---------------- Phase Z / ACC per segment ----------------------------
    const int segB[4] = {0, 2048, 3072, 4096};
    for (int sg = 0; sg < 3; ++sg) {
        int sBeg = segB[sg];
        int nc   = (segB[sg + 1] - sBeg) >> 8;   // chunks of 256 neurons
        // ---- pass A: Z (half-chunk pipelined) ----
        float zc[2][4] = {};
        {
            LOADH(qa, sBeg + wave * 32)
            for (int c = 0; c < nc; ++c) {
                int n0 = sBeg + c * 256 + wave * 32;
                f32x4 acc[2][2];
                acc[0][0] = z4; acc[0][1] = z4; acc[1][0] = z4; acc[1][1] = z4;
                LOADH(qb, n0 + 16)
                MFMAH(qa, 0)
                if (c + 1 < nc) { LOADH(qa, n0 + 256) }
                MFMAH(qb, 1)
#pragma unroll
                for (int rt = 0; rt < 2; ++rt)
#pragma unroll
                    for (int r = 0; r < 4; ++r)
                        zc[rt][r] += __expf(acc[rt][0][r]) + __expf(acc[rt][1][r]);
            }
        }
        // reduce over the 16 l15-lanes (cols within wave)
#pragma unroll
        for (int rt = 0; rt < 2; ++rt)
#pragma unroll
            for (int r = 0; r < 4; ++r) {
                float z = zc[rt][r];
#pragma unroll
                for (int m = 1; m < 16; m <<= 1) z += __shfl_xor(z, m);
                zc[rt][r] = z;
            }
        if (l15 == 0) {
#pragma unroll
            for (int rt = 0; rt < 2; ++rt)
#pragma unroll
                for (int r = 0; r < 4; ++r)
                    zs[wave][kg][rt * 4 + r] = zc[rt][r];
        }
        __syncthreads();
        float cf[2][4];
#pragma unroll
        for (int rt = 0; rt < 2; ++rt)
#pragma unroll
            for (int r = 0; r < 4; ++r) {
                float z = 0.f;
#pragma unroll
                for (int w = 0; w < 8; ++w) z += zs[w][kg][rt * 4 + r];
                cf[rt][r] = imp[row0 + rt * 16 + kg * 4 + r] / z;
            }
        __syncthreads();  // zs reused next segment
        // ---- pass B: accumulate coef*exp(l) -> atomicAdd dacc ----
        {
            LOADH(qa, sBeg + wave * 32)
            for (int c = 0; c < nc; ++c) {
                int n0 = sBeg + c * 256 + wave * 32;
                f32x4 acc[2][2];
                acc[0][0] = z4; acc[0][1] = z4; acc[1][0] = z4; acc[1][1] = z4;
                LOADH(qb, n0 + 16)
                MFMAH(qa, 0)
                if (c + 1 < nc) { LOADH(qa, n0 + 256) }
                MFMAH(qb, 1)
                float s0 = 0.f, s1 = 0.f;
#pragma unroll
                for (int rt = 0; rt < 2; ++rt)
#pragma unroll
                    for (int r = 0; r < 4; ++r) {
                        s0 += cf[rt][r] * __expf(acc[rt][0][r]);
                        s1 += cf[rt][r] * __expf(acc[rt][1][r]);
                    }
                // sum the 4 kg row-groups (lane bits 4,5)
                s0 += __shfl_xor(s0, 16); s0 += __shfl_xor(s0, 32);
                s1 += __shfl_xor(s1, 16); s1 += __shfl_xor(s1, 32);
                if (kg == 0) {
                    atomicAdd(&dbase[n0 + l15],      s0);
                    atomicAdd(&dbase[n0 + 16 + l15], s1);
                }
            }
        }
    }
#undef LOADH
#undef MFMAH
}

// ---------------------------------------------------------------------------
// K2: top-k sparsify; one block per (batch, segment) -> 12 blocks.
__global__ __launch_bounds__(256) void k_topk(const float* __restrict__ dacc,
                                              float* __restrict__ out) {
    __shared__ float dv[2048];
    __shared__ float redv[4];
    __shared__ int   redi[4];
    __shared__ float selv[8];
    __shared__ int   seli[8];
    int blk = blockIdx.x;
    int b   = blk / 3;
    int sg  = blk - 3 * b;
    int t   = threadIdx.x;
    const int segStart[3] = {0, 2048, 3072};
    const int segLen[3]   = {2048, 1024, 1024};
    const int segK[3]     = {8, 4, 6};
    const int segOut[3]   = {0, 2048, 4096};
    int st = segStart[sg], len = segLen[sg], kk = segK[sg];
    for (int n = t; n < len; n += 256) dv[n] = dacc[b * 4096 + st + n];
    __syncthreads();
    for (int it = 0; it < kk; ++it) {
        float bv = -3.0e38f;
        int   bi = 1 << 30;
        for (int n = t; n < len; n += 256) {
            float v = dv[n];
            if (v > bv) { bv = v; bi = n; }  // strict > keeps lowest idx
        }
#pragma unroll
        for (int m = 1; m < 64; m <<= 1) {
            float ov = __shfl_xor(bv, m);
            int   oi = __shfl_xor(bi, m);
            if (ov > bv || (ov == bv && oi < bi)) { bv = ov; bi = oi; }
        }
        if ((t & 63) == 0) { redv[t >> 6] = bv; redi[t >> 6] = bi; }
        __syncthreads();
        if (t == 0) {
            for (int w = 1; w < 4; ++w)
                if (redv[w] > bv || (redv[w] == bv && redi[w] < bi)) {
                    bv = redv[w]; bi = redi[w];
                }
            selv[it] = bv;
            seli[it] = bi;
            dv[bi] = -3.4e38f;
        }
        __syncthreads();
    }
    float sum = 0.f;
    for (int it = 0; it < kk; ++it) sum += selv[it];
    float inv = 1.0f / (sum + 1e-8f);
    for (int n = t; n < len; n += 256) {
        float v = 0.0f;
        for (int it = 0; it < kk; ++it)
            if (seli[it] == n) v = selv[it] * inv;
        out[b * 5120 + segOut[sg] + n] = v;
        if (sg == 1) out[b * 5120 + 3072 + n] = v;  // wK == wQ
    }
}

// ---------------------------------------------------------------------------
extern "C" void kernel_launch(void* const* d_in, const int* in_sizes, int n_in,
                              void* d_out, int out_size, void* d_ws, size_t ws_size,
                              hipStream_t stream) {
    (void)in_sizes; (void)n_in; (void)out_size; (void)ws_size;
    const float* x    = (const float*)d_in[0];
    const float* imp  = (const float*)d_in[1];
    const float* W    = (const float*)d_in[2];
    const float* bias = (const float*)d_in[3];
    const float* emb  = (const float*)d_in[4];
    float* out = (float*)d_out;

    // workspace layout (bytes): ~1.6 MB
    char* w = (char*)d_ws;
    __bf16* e_hi  = (__bf16*)w;  w += (size_t)4096 * 64 * 2;   // 512KB
    __bf16* e_lo  = (__bf16*)w;  w += (size_t)4096 * 64 * 2;   // 512KB
    __bf16* wt_hi = (__bf16*)w;  w += (size_t)64 * 2048 * 2;   // 256KB
    __bf16* wt_lo = (__bf16*)w;  w += (size_t)64 * 2048 * 2;   // 256KB
    float*  dacc  = (float*)w;   w += (size_t)4 * 4096 * 4;    // 64KB

    hipLaunchKernelGGL(k_prep,  dim3(1600), dim3(256), 0, stream,
                       emb, W, e_hi, e_lo, wt_hi, wt_lo, dacc);
    hipLaunchKernelGGL(k_fused, dim3(512),  dim3(512), 0, stream,
                       x, wt_hi, wt_lo, bias, e_hi, e_lo, imp, dacc);
    hipLaunchKernelGGL(k_topk,  dim3(12),   dim3(256), 0, stream,
                       dacc, out);
}